// Round 4
// baseline (55.287 us; speedup 1.0000x reference)
//
#include <hip/hip_runtime.h>

#define BB   8
#define RR   128
#define SS   512
#define DD   33
#define EE   128
#define HH   4
#define EKK  32
#define NHH  128
#define HD   (HH*DD)      // 132

// ---- workspace layout (float offsets) ----
#define WS_SA   0
#define WS_QP   64                               // B*R*E  = 131072 (row-major)
#define WS_KT   (WS_QP  + BB*RR*EE)              // B*E*S  = 524288 (transposed)
#define WS_VT   (WS_KT  + BB*EE*SS)              // B*D*S  = 135168
#define WS_MB   (WS_VT  + BB*DD*SS)              // B*D*16 u32 = 4224 words
#define WS_WOT  (WS_MB  + BB*DD*16)              // HD*NH  = 16896
#define WS_E    (WS_WOT + HD*NHH)                // B*H*R*S = 2097152
// total ~2.9M floats = 11.6 MB

#define NB_SA   1
#define NB_QP   (BB*RR/8)                        // 128
#define NB_KT   (BB*SS/16)                       // 256
#define NB_VT   ((BB*DD*SS + 127)/128)           // 1056
#define NB_MB   ((BB*DD*16 + 127)/128)           // 33
#define NB_WOT  ((HD*NHH + 127)/128)             // 132
#define NB_PREP (NB_SA + NB_QP + NB_KT + NB_VT + NB_MB + NB_WOT)

// ============================================================== K1: prep
__global__ __launch_bounds__(128) void prep_kernel(
    const float* __restrict__ query, const float* __restrict__ key,
    const float* __restrict__ value, const float* __restrict__ mask,
    const float* __restrict__ stridev,
    const float* __restrict__ Wq, const float* __restrict__ bq,
    const float* __restrict__ Wk, const float* __restrict__ bk,
    const float* __restrict__ Wr, const float* __restrict__ brv,
    const float* __restrict__ Wo,
    float* __restrict__ ws, float* __restrict__ out_tail)
{
    __shared__ float rows[16 * EE];    // 8 KB
    int blk = blockIdx.x, tid = threadIdx.x;

    if (blk == 0) {                    // ---- sa (D=33)
        if (tid < DD) {
            float acc = brv[tid];
#pragma unroll
            for (int j = 0; j < DD; ++j) acc += stridev[j] * Wr[tid * DD + j];
            float sv = 1.0f / (1.0f + __expf(-acc));
            ws[WS_SA + tid] = sv;
            out_tail[tid]   = sv;
        }
        return;
    }
    blk -= NB_SA;

    if (blk < NB_QP) {                 // ---- q proj, 8 rows -> qp[b,r,e]
        int br0 = blk * 8;
#pragma unroll
        for (int p = 0; p < 8; ++p) rows[p * EE + tid] = query[(br0 + p) * EE + tid];
        __syncthreads();
        float acc[8];
        float bv = bq[tid];
#pragma unroll
        for (int p = 0; p < 8; ++p) acc[p] = bv;
        const float4* W4 = (const float4*)(Wq + tid * EE);
        const float4* R4 = (const float4*)rows;
#pragma unroll
        for (int j = 0; j < EE / 4; ++j) {
            float4 w = W4[j];
#pragma unroll
            for (int p = 0; p < 8; ++p) {
                float4 rv = R4[p * 32 + j];
                acc[p] += w.x * rv.x + w.y * rv.y + w.z * rv.z + w.w * rv.w;
            }
        }
#pragma unroll
        for (int p = 0; p < 8; ++p)
            ws[WS_QP + (br0 + p) * EE + tid] = acc[p];
        return;
    }
    blk -= NB_QP;

    if (blk < NB_KT) {                 // ---- k proj, 16 rows -> kt[b,e,s]
        int s16 = blk * 16;
#pragma unroll
        for (int p = 0; p < 16; ++p) rows[p * EE + tid] = key[(s16 + p) * EE + tid];
        __syncthreads();
        float acc[16];
        float bv = bk[tid];
#pragma unroll
        for (int p = 0; p < 16; ++p) acc[p] = bv;
        const float4* W4 = (const float4*)(Wk + tid * EE);
        const float4* R4 = (const float4*)rows;
#pragma unroll
        for (int j = 0; j < EE / 4; ++j) {
            float4 w = W4[j];
#pragma unroll
            for (int p = 0; p < 16; ++p) {
                float4 rv = R4[p * 32 + j];
                acc[p] += w.x * rv.x + w.y * rv.y + w.z * rv.z + w.w * rv.w;
            }
        }
        int b = s16 / SS, s0 = s16 % SS;
        float4* dst = (float4*)(ws + WS_KT + (b * EE + tid) * SS + s0);
#pragma unroll
        for (int q4 = 0; q4 < 4; ++q4) {
            float4 v; v.x = acc[q4*4]; v.y = acc[q4*4+1]; v.z = acc[q4*4+2]; v.w = acc[q4*4+3];
            dst[q4] = v;
        }
        return;
    }
    blk -= NB_KT;

    if (blk < NB_VT) {                 // ---- value transpose -> vt[b,d,s]
        int gid = blk * 128 + tid;
        if (gid < BB * DD * SS) {
            int s = gid % SS, rem = gid / SS;
            int d = rem % DD, b = rem / DD;
            ws[WS_VT + gid] = value[(b * SS + s) * DD + d];
        }
        return;
    }
    blk -= NB_VT;

    if (blk < NB_MB) {                 // ---- mask -> bit-pack mb[b][d][16]
        int w = blk * 128 + tid;
        if (w < BB * DD * 16) {
            int b   = w / (DD * 16);
            int rem = w - b * (DD * 16);
            int d   = rem >> 4;
            int wi  = rem & 15;
            unsigned bits = 0;
#pragma unroll
            for (int j = 0; j < 32; ++j) {
                int s = wi * 32 + j;
                if (mask[(b * SS + s) * DD + d] != 0.f) bits |= (1u << j);
            }
            ((unsigned*)(ws + WS_MB))[w] = bits;
        }
        return;
    }
    blk -= NB_MB;

    {                                  // ---- Wo transpose -> wot[j][n]
        int gid = blk * 128 + tid;
        if (gid < HD * NHH) {
            int n = gid & 127, j = gid >> 7;
            ws[WS_WOT + gid] = Wo[n * HD + j];
        }
    }
}

// ======================== K2: scores -> E = exp(score/sqrt(EK)) (tiled)
// blk = bh*16 + rt*2 + st ; bh in [0,32), rt in [0,8), st in [0,2)
__global__ __launch_bounds__(256) void scores_kernel(
    const float* __restrict__ qp, const float* __restrict__ kt,
    float* __restrict__ E)
{
    __shared__ float s_q[16 * EKK];    // 2 KB
    int blk = blockIdx.x, tid = threadIdx.x;
    int st = blk & 1;
    int rt = (blk >> 1) & 7;
    int bh = blk >> 4;
    int b = bh >> 2, h = bh & 3;
    int s0 = st * 256, r0 = rt * 16;

    // stage q tile: 16 r x 32 e
#pragma unroll
    for (int k = 0; k < 2; ++k) {
        int idx = k * 256 + tid;
        int p = idx >> 5, e = idx & 31;
        s_q[p * EKK + e] = qp[(b * RR + r0 + p) * EE + h * EKK + e];
    }
    __syncthreads();

    // k column for this thread's s, straight from global (coalesced)
    float kr[32];
    const float* kbase = kt + (b * EE + h * EKK) * SS + s0 + tid;
#pragma unroll
    for (int e = 0; e < 32; ++e) kr[e] = kbase[e * SS];

    const float scale = 0.17677669529663687f;   // 1/sqrt(32)
    float* Eout = E + ((b * HH + h) * RR + r0) * SS + s0 + tid;
    const float4* q4 = (const float4*)s_q;
#pragma unroll
    for (int rr = 0; rr < 16; rr += 2) {
        float a0 = 0.f, a1 = 0.f;
#pragma unroll
        for (int eq = 0; eq < 8; ++eq) {
            float4 qa = q4[rr * 8 + eq];
            float4 qb = q4[rr * 8 + 8 + eq];
            a0 += qa.x * kr[eq*4] + qa.y * kr[eq*4+1] + qa.z * kr[eq*4+2] + qa.w * kr[eq*4+3];
            a1 += qb.x * kr[eq*4] + qb.y * kr[eq*4+1] + qb.z * kr[eq*4+2] + qb.w * kr[eq*4+3];
        }
        Eout[rr * SS]       = __expf(a0 * scale);
        Eout[(rr + 1) * SS] = __expf(a1 * scale);
    }
}

// ================= K3: masked softmax + PV + out-GEMV, one block per (b,r)
__global__ __launch_bounds__(512) void softpv_kernel(
    const float* __restrict__ E, const float* __restrict__ vt,
    const unsigned* __restrict__ mb, const float* __restrict__ tt,
    const float* __restrict__ qt, const float* __restrict__ sa,
    const float* __restrict__ wot, const float* __restrict__ bo,
    float* __restrict__ out)
{
    __shared__ float s_e[HH * SS];     // 8 KB
    __shared__ float s_tt[SS];         // 2 KB
    __shared__ float s_sa[DD];
    __shared__ unsigned s_mb[DD * 16]; // 2112 B
    __shared__ float s_x[HD];
    __shared__ float s_part[4][NHH];   // 2 KB

    int brid = blockIdx.x;
    int b = brid >> 7, r = brid & 127;
    int tid = threadIdx.x;

    // stage E rows for this (b,r): 4 heads x 512 = 512 float4
    ((float4*)s_e)[tid] =
        ((const float4*)(E + ((b * HH + (tid >> 7)) * RR + r) * SS))[tid & 127];
    if (tid < 128) ((float4*)s_tt)[tid] = ((const float4*)(tt + b * SS))[tid];
    if (tid < DD) s_sa[tid] = sa[tid];
    for (int i = tid; i < DD * 16; i += 512) s_mb[i] = mb[b * DD * 16 + i];
    __syncthreads();

    int wave = tid >> 6, lane = tid & 63;
    float qtr = qt[r];
#pragma unroll
    for (int rd = 0; rd < 5; ++rd) {
        int d = rd * 8 + wave;
        if (d < DD) {
            float sad = s_sa[d];
            float lo = qtr - sad, hi = qtr + sad;

            unsigned mw    = s_mb[d * 16 + (lane >> 2)];
            unsigned mbyte = (mw >> ((lane & 3) * 8)) & 0xFFu;

            int sb = lane * 8;
            const float4* vv4 = (const float4*)(vt + (b * DD + d) * SS + sb);
            float4 v0 = vv4[0], v1 = vv4[1];
            const float4* t4 = (const float4*)(s_tt + sb);
            float4 t0 = t4[0], t1 = t4[1];

            float tv[8] = {t0.x,t0.y,t0.z,t0.w,t1.x,t1.y,t1.z,t1.w};
            float vv[8] = {v0.x,v0.y,v0.z,v0.w,v1.x,v1.y,v1.z,v1.w};
            bool  mk[8];
#pragma unroll
            for (int i = 0; i < 8; ++i)
                mk[i] = ((mbyte >> i) & 1u) && (tv[i] >= lo) & (tv[i] <= hi);

            float psum[HH] = {0,0,0,0}, wsum[HH] = {0,0,0,0};
#pragma unroll
            for (int h = 0; h < HH; ++h) {
                const float4* e4 = (const float4*)(s_e + h * SS + sb);
                float4 e0 = e4[0], e1 = e4[1];
                float ev[8] = {e0.x,e0.y,e0.z,e0.w,e1.x,e1.y,e1.z,e1.w};
#pragma unroll
                for (int i = 0; i < 8; ++i) {
                    float p = mk[i] ? ev[i] : 0.f;
                    psum[h] += p;
                    wsum[h] += p * vv[i];
                }
            }
#pragma unroll
            for (int off = 32; off; off >>= 1) {
#pragma unroll
                for (int h = 0; h < HH; ++h) {
                    psum[h] += __shfl_xor(psum[h], off);
                    wsum[h] += __shfl_xor(wsum[h], off);
                }
            }

            // all-masked fallback: softmax of all-NEG -> uniform -> mean(v)
            bool anyz = (psum[0]==0.f) | (psum[1]==0.f) |
                        (psum[2]==0.f) | (psum[3]==0.f);
            float vall = 0.f;
            if (anyz) {
#pragma unroll
                for (int i = 0; i < 8; ++i) vall += vv[i];
#pragma unroll
                for (int off = 32; off; off >>= 1) vall += __shfl_xor(vall, off);
            }

            if (lane == 0) {
#pragma unroll
                for (int h = 0; h < HH; ++h)
                    s_x[h * DD + d] = (psum[h] > 0.f) ? (wsum[h] / psum[h])
                                                      : (vall * (1.0f / SS));
            }
        }
    }
    __syncthreads();

    // ---- out[n] = x . Wo[n,:] + bo[n], 4-way j-split
    {
        int g = tid >> 7, n = tid & 127;
        float acc = 0.f;
#pragma unroll
        for (int j = 0; j < 33; ++j)
            acc += s_x[g * 33 + j] * wot[(g * 33 + j) * NHH + n];
        s_part[g][n] = acc;
    }
    __syncthreads();
    if (tid < NHH)
        out[brid * NHH + tid] = bo[tid] + s_part[0][tid] + s_part[1][tid]
                              + s_part[2][tid] + s_part[3][tid];
}

// ================================================================== launch
extern "C" void kernel_launch(void* const* d_in, const int* in_sizes, int n_in,
                              void* d_out, int out_size, void* d_ws, size_t ws_size,
                              hipStream_t stream) {
    const float* query   = (const float*)d_in[0];
    const float* key     = (const float*)d_in[1];
    const float* value   = (const float*)d_in[2];
    const float* mask    = (const float*)d_in[3];
    const float* qt      = (const float*)d_in[4];
    const float* tt      = (const float*)d_in[5];
    const float* stridev = (const float*)d_in[6];
    const float* Wq      = (const float*)d_in[7];
    const float* bq      = (const float*)d_in[8];
    const float* Wk      = (const float*)d_in[9];
    const float* bk      = (const float*)d_in[10];
    const float* Wr      = (const float*)d_in[11];
    const float* brv     = (const float*)d_in[12];
    const float* Wo      = (const float*)d_in[13];
    const float* bo      = (const float*)d_in[14];

    float* out = (float*)d_out;               // 131072 out + 33 sa
    float* ws  = (float*)d_ws;

    prep_kernel<<<NB_PREP, 128, 0, stream>>>(
        query, key, value, mask, stridev, Wq, bq, Wk, bk, Wr, brv, Wo,
        ws, out + BB * RR * NHH);
    scores_kernel<<<512, 256, 0, stream>>>(ws + WS_QP, ws + WS_KT, ws + WS_E);
    softpv_kernel<<<BB * RR, 512, 0, stream>>>(
        ws + WS_E, ws + WS_VT, (const unsigned*)(ws + WS_MB),
        tt, qt, ws + WS_SA, ws + WS_WOT, bo, out);
}

// Round 6
// 51.407 us; speedup vs baseline: 1.0755x; 1.0755x over previous
//
#include <hip/hip_runtime.h>

#define BB   8
#define RR   128
#define SS   512
#define DD   33
#define EE   128
#define HH   4
#define EKK  32
#define NHH  128
#define HD   (HH*DD)      // 132

// ---- workspace layout (float offsets) ----
#define WS_SA   0
#define WS_QP   64                               // B*R*E  = 131072 (row-major)
#define WS_KT   (WS_QP  + BB*RR*EE)              // B*E*S  = 524288 (transposed)
#define WS_VT   (WS_KT  + BB*EE*SS)              // B*D*S  = 135168
#define WS_MB   (WS_VT  + BB*DD*SS)              // B*D*16 u32 = 4224 words
#define WS_WOT  (WS_MB  + BB*DD*16)              // HD*NH  = 16896

#define NB_SA   1
#define NB_QP   (BB*RR/8)                        // 128
#define NB_KT   (BB*SS/16)                       // 256
#define NB_VT   ((BB*DD*SS + 127)/128)           // 1056
#define NB_MB   ((BB*DD*16 + 127)/128)           // 33
#define NB_WOT  ((HD*NHH + 127)/128)             // 132
#define NB_PREP (NB_SA + NB_QP + NB_KT + NB_VT + NB_MB + NB_WOT)

// ============================================================== K1: prep
__global__ __launch_bounds__(128) void prep_kernel(
    const float* __restrict__ query, const float* __restrict__ key,
    const float* __restrict__ value, const float* __restrict__ mask,
    const float* __restrict__ stridev,
    const float* __restrict__ Wq, const float* __restrict__ bq,
    const float* __restrict__ Wk, const float* __restrict__ bk,
    const float* __restrict__ Wr, const float* __restrict__ brv,
    const float* __restrict__ Wo,
    float* __restrict__ ws, float* __restrict__ out_tail)
{
    __shared__ float rows[16 * EE];    // 8 KB
    int blk = blockIdx.x, tid = threadIdx.x;

    if (blk == 0) {                    // ---- sa (D=33)
        if (tid < DD) {
            float acc = brv[tid];
#pragma unroll
            for (int j = 0; j < DD; ++j) acc += stridev[j] * Wr[tid * DD + j];
            float sv = 1.0f / (1.0f + __expf(-acc));
            ws[WS_SA + tid] = sv;
            out_tail[tid]   = sv;
        }
        return;
    }
    blk -= NB_SA;

    if (blk < NB_QP) {                 // ---- q proj, 8 rows -> qp[b,r,e]
        int br0 = blk * 8;
#pragma unroll
        for (int p = 0; p < 8; ++p) rows[p * EE + tid] = query[(br0 + p) * EE + tid];
        __syncthreads();
        float acc[8];
        float bv = bq[tid];
#pragma unroll
        for (int p = 0; p < 8; ++p) acc[p] = bv;
        const float4* W4 = (const float4*)(Wq + tid * EE);
        const float4* R4 = (const float4*)rows;
#pragma unroll
        for (int j = 0; j < EE / 4; ++j) {
            float4 w = W4[j];
#pragma unroll
            for (int p = 0; p < 8; ++p) {
                float4 rv = R4[p * 32 + j];
                acc[p] += w.x * rv.x + w.y * rv.y + w.z * rv.z + w.w * rv.w;
            }
        }
#pragma unroll
        for (int p = 0; p < 8; ++p)
            ws[WS_QP + (br0 + p) * EE + tid] = acc[p];
        return;
    }
    blk -= NB_QP;

    if (blk < NB_KT) {                 // ---- k proj, 16 rows -> kt[b,e,s]
        int s16 = blk * 16;
#pragma unroll
        for (int p = 0; p < 16; ++p) rows[p * EE + tid] = key[(s16 + p) * EE + tid];
        __syncthreads();
        float acc[16];
        float bv = bk[tid];
#pragma unroll
        for (int p = 0; p < 16; ++p) acc[p] = bv;
        const float4* W4 = (const float4*)(Wk + tid * EE);
        const float4* R4 = (const float4*)rows;
#pragma unroll
        for (int j = 0; j < EE / 4; ++j) {
            float4 w = W4[j];
#pragma unroll
            for (int p = 0; p < 16; ++p) {
                float4 rv = R4[p * 32 + j];
                acc[p] += w.x * rv.x + w.y * rv.y + w.z * rv.z + w.w * rv.w;
            }
        }
        int b = s16 / SS, s0 = s16 % SS;
        float4* dst = (float4*)(ws + WS_KT + (b * EE + tid) * SS + s0);
#pragma unroll
        for (int q4 = 0; q4 < 4; ++q4) {
            float4 v; v.x = acc[q4*4]; v.y = acc[q4*4+1]; v.z = acc[q4*4+2]; v.w = acc[q4*4+3];
            dst[q4] = v;
        }
        return;
    }
    blk -= NB_KT;

    if (blk < NB_VT) {                 // ---- value transpose -> vt[b,d,s]
        int gid = blk * 128 + tid;
        if (gid < BB * DD * SS) {
            int s = gid % SS, rem = gid / SS;
            int d = rem % DD, b = rem / DD;
            ws[WS_VT + gid] = value[(b * SS + s) * DD + d];
        }
        return;
    }
    blk -= NB_VT;

    if (blk < NB_MB) {                 // ---- mask -> bit-pack mb[b][d][16]
        int w = blk * 128 + tid;
        if (w < BB * DD * 16) {
            int b   = w / (DD * 16);
            int rem = w - b * (DD * 16);
            int d   = rem >> 4;
            int wi  = rem & 15;
            unsigned bits = 0;
#pragma unroll
            for (int j = 0; j < 32; ++j) {
                int s = wi * 32 + j;
                if (mask[(b * SS + s) * DD + d] != 0.f) bits |= (1u << j);
            }
            ((unsigned*)(ws + WS_MB))[w] = bits;
        }
        return;
    }
    blk -= NB_MB;

    {                                  // ---- Wo transpose -> wot[j][n]
        int gid = blk * 128 + tid;
        if (gid < HD * NHH) {
            int n = gid & 127, j = gid >> 7;
            ws[WS_WOT + gid] = Wo[n * HD + j];
        }
    }
}

// ============ K2: scores + masked softmax + PV + out-GEMV, 2 r per block
__global__ __launch_bounds__(512) void fused_kernel(
    const float* __restrict__ qp, const float* __restrict__ kt,
    const float* __restrict__ vt, const unsigned* __restrict__ mb,
    const float* __restrict__ tt, const float* __restrict__ qt,
    const float* __restrict__ sa, const float* __restrict__ wot,
    const float* __restrict__ bo, float* __restrict__ out)
{
    __shared__ float s_q[2][EE];           // 1 KB
    __shared__ float s_tt[SS];             // 2 KB
    __shared__ float s_sa[DD];
    __shared__ unsigned s_mb[DD * 16];     // 2112 B
    __shared__ float s_e[2][HH][SS];       // 16 KB
    __shared__ float s_x[2][HD];           // 1056 B
    __shared__ float s_part[4][NHH];       // 2 KB

    int blk = blockIdx.x;
    int b  = blk >> 6;                     // 64 r-tiles per batch
    int r0 = (blk & 63) * 2;
    int tid = threadIdx.x;

    if (tid < 256) s_q[tid >> 7][tid & 127] =
        qp[(b * RR + r0 + (tid >> 7)) * EE + (tid & 127)];
    s_tt[tid] = tt[b * SS + tid];
    if (tid < DD) s_sa[tid] = sa[tid];
    for (int i = tid; i < DD * 16; i += 512)           // FIXED: full coverage
        s_mb[i] = mb[b * DD * 16 + i];
    __syncthreads();

    // ---- phase A: E[r][h][s] = exp(score) into LDS
    {
        int h = tid >> 7, sq = tid & 127;        // 4 s per thread
        const float4* ktb = (const float4*)kt + (b * EE + h * EKK) * (SS / 4) + sq;
        float4 a0 = {0.f,0.f,0.f,0.f}, a1 = {0.f,0.f,0.f,0.f};
#pragma unroll
        for (int e = 0; e < EKK; ++e) {
            float4 kv = ktb[e * (SS / 4)];
            float q0 = s_q[0][h * EKK + e];
            float q1 = s_q[1][h * EKK + e];
            a0.x += q0 * kv.x; a0.y += q0 * kv.y; a0.z += q0 * kv.z; a0.w += q0 * kv.w;
            a1.x += q1 * kv.x; a1.y += q1 * kv.y; a1.z += q1 * kv.z; a1.w += q1 * kv.w;
        }
        const float scale = 0.17677669529663687f;    // 1/sqrt(32)
        float4 e0, e1;
        e0.x = __expf(a0.x * scale); e0.y = __expf(a0.y * scale);
        e0.z = __expf(a0.z * scale); e0.w = __expf(a0.w * scale);
        e1.x = __expf(a1.x * scale); e1.y = __expf(a1.y * scale);
        e1.z = __expf(a1.z * scale); e1.w = __expf(a1.w * scale);
        ((float4*)s_e[0][h])[sq] = e0;
        ((float4*)s_e[1][h])[sq] = e1;
    }
    __syncthreads();

    // ---- phase B: per-d masked softmax + PV; vt row loaded once per d
    int wave = tid >> 6, lane = tid & 63;
    float qtr2[2] = { qt[r0], qt[r0 + 1] };
#pragma unroll
    for (int rd = 0; rd < 5; ++rd) {
        int d = rd * 8 + wave;
        if (d < DD) {
            float sad = s_sa[d];
            unsigned mw    = s_mb[d * 16 + (lane >> 2)];
            unsigned mbyte = (mw >> ((lane & 3) * 8)) & 0xFFu;

            int sb = lane * 8;
            const float4* vv4 = (const float4*)(vt + (b * DD + d) * SS + sb);
            float4 v0 = vv4[0], v1 = vv4[1];
            const float4* t4 = (const float4*)(s_tt + sb);
            float4 t0 = t4[0], t1 = t4[1];
            float tv[8] = {t0.x,t0.y,t0.z,t0.w,t1.x,t1.y,t1.z,t1.w};
            float vv[8] = {v0.x,v0.y,v0.z,v0.w,v1.x,v1.y,v1.z,v1.w};

#pragma unroll
            for (int rr = 0; rr < 2; ++rr) {
                float lo = qtr2[rr] - sad, hi = qtr2[rr] + sad;
                bool mk[8];
#pragma unroll
                for (int i = 0; i < 8; ++i)
                    mk[i] = ((mbyte >> i) & 1u) && (tv[i] >= lo) & (tv[i] <= hi);

                float psum[HH] = {0,0,0,0}, wsum[HH] = {0,0,0,0};
#pragma unroll
                for (int h = 0; h < HH; ++h) {
                    const float4* e4 = (const float4*)(s_e[rr][h] + sb);
                    float4 e0 = e4[0], e1 = e4[1];
                    float ev[8] = {e0.x,e0.y,e0.z,e0.w,e1.x,e1.y,e1.z,e1.w};
#pragma unroll
                    for (int i = 0; i < 8; ++i) {
                        float p = mk[i] ? ev[i] : 0.f;
                        psum[h] += p;
                        wsum[h] += p * vv[i];
                    }
                }
#pragma unroll
                for (int off = 32; off; off >>= 1) {
#pragma unroll
                    for (int h = 0; h < HH; ++h) {
                        psum[h] += __shfl_xor(psum[h], off);
                        wsum[h] += __shfl_xor(wsum[h], off);
                    }
                }

                bool anyz = (psum[0]==0.f) | (psum[1]==0.f) |
                            (psum[2]==0.f) | (psum[3]==0.f);
                float vall = 0.f;
                if (anyz) {
#pragma unroll
                    for (int i = 0; i < 8; ++i) vall += vv[i];
#pragma unroll
                    for (int off = 32; off; off >>= 1) vall += __shfl_xor(vall, off);
                }

                if (lane == 0) {
#pragma unroll
                    for (int h = 0; h < HH; ++h)
                        s_x[rr][h * DD + d] = (psum[h] > 0.f)
                            ? (wsum[h] / psum[h]) : (vall * (1.0f / SS));
                }
            }
        }
    }
    __syncthreads();

    // ---- phase C: out GEMV for both r (j split 2x66)
    {
        int g2 = tid >> 7;                 // 0..3 : rr = g2>>1, jg = g2&1
        int rr = g2 >> 1, jg = g2 & 1;
        int n = tid & 127;
        float acc = 0.f;
#pragma unroll
        for (int j = 0; j < 66; ++j)
            acc += s_x[rr][jg * 66 + j] * wot[(jg * 66 + j) * NHH + n];
        s_part[g2][n] = acc;
    }
    __syncthreads();
    if (tid < 256) {
        int rr = tid >> 7, n = tid & 127;
        out[(b * RR + r0 + rr) * NHH + n] =
            bo[n] + s_part[rr * 2][n] + s_part[rr * 2 + 1][n];
    }
}

// ================================================================== launch
extern "C" void kernel_launch(void* const* d_in, const int* in_sizes, int n_in,
                              void* d_out, int out_size, void* d_ws, size_t ws_size,
                              hipStream_t stream) {
    const float* query   = (const float*)d_in[0];
    const float* key     = (const float*)d_in[1];
    const float* value   = (const float*)d_in[2];
    const float* mask    = (const float*)d_in[3];
    const float* qt      = (const float*)d_in[4];
    const float* tt      = (const float*)d_in[5];
    const float* stridev = (const float*)d_in[6];
    const float* Wq      = (const float*)d_in[7];
    const float* bq      = (const float*)d_in[8];
    const float* Wk      = (const float*)d_in[9];
    const float* bk      = (const float*)d_in[10];
    const float* Wr      = (const float*)d_in[11];
    const float* brv     = (const float*)d_in[12];
    const float* Wo      = (const float*)d_in[13];
    const float* bo      = (const float*)d_in[14];

    float* out = (float*)d_out;               // 131072 out + 33 sa
    float* ws  = (float*)d_ws;

    prep_kernel<<<NB_PREP, 128, 0, stream>>>(
        query, key, value, mask, stridev, Wq, bq, Wk, bk, Wr, brv, Wo,
        ws, out + BB * RR * NHH);
    fused_kernel<<<BB * 64, 512, 0, stream>>>(
        ws + WS_QP, ws + WS_KT, ws + WS_VT, (const unsigned*)(ws + WS_MB),
        tt, qt, ws + WS_SA, ws + WS_WOT, bo, out);
}

// Round 7
// 40.016 us; speedup vs baseline: 1.3816x; 1.2847x over previous
//
#include <hip/hip_runtime.h>

#define BB   8
#define RR   128
#define SS   512
#define DD   33
#define EE   128
#define HH   4
#define EKK  32
#define NHH  128
#define HD   (HH*DD)      // 132

// ---- workspace layout (float offsets) ----
#define WS_SA   0
#define WS_QP   64                               // B*R*E  = 131072 (row-major)
#define WS_KT   (WS_QP  + BB*RR*EE)              // B*E*S  = 524288 (transposed)
#define WS_WOT  (WS_KT  + BB*EE*SS)              // HD*NH  = 16896

#define NB_SA   1
#define NB_QP   (BB*RR/8)                        // 128
#define NB_KT   (BB*SS/16)                       // 256
#define NB_WOT  ((HD*NHH + 127)/128)             // 132
#define NB_PREP (NB_SA + NB_QP + NB_KT + NB_WOT) // 517

// ============================================================== K1: prep
__global__ __launch_bounds__(128) void prep_kernel(
    const float* __restrict__ query, const float* __restrict__ key,
    const float* __restrict__ stridev,
    const float* __restrict__ Wq, const float* __restrict__ bq,
    const float* __restrict__ Wk, const float* __restrict__ bk,
    const float* __restrict__ Wr, const float* __restrict__ brv,
    const float* __restrict__ Wo,
    float* __restrict__ ws, float* __restrict__ out_tail)
{
    __shared__ float rows[16 * EE];    // 8 KB
    int blk = blockIdx.x, tid = threadIdx.x;

    if (blk == 0) {                    // ---- sa (D=33)
        if (tid < DD) {
            float acc = brv[tid];
#pragma unroll
            for (int j = 0; j < DD; ++j) acc += stridev[j] * Wr[tid * DD + j];
            float sv = 1.0f / (1.0f + __expf(-acc));
            ws[WS_SA + tid] = sv;
            out_tail[tid]   = sv;
        }
        return;
    }
    blk -= NB_SA;

    if (blk < NB_QP) {                 // ---- q proj, 8 rows -> qp[b,r,e]
        int br0 = blk * 8;
#pragma unroll
        for (int p = 0; p < 8; ++p) rows[p * EE + tid] = query[(br0 + p) * EE + tid];
        __syncthreads();
        float acc[8];
        float bv = bq[tid];
#pragma unroll
        for (int p = 0; p < 8; ++p) acc[p] = bv;
        const float4* W4 = (const float4*)(Wq + tid * EE);
        const float4* R4 = (const float4*)rows;
#pragma unroll
        for (int j = 0; j < EE / 4; ++j) {
            float4 w = W4[j];
#pragma unroll
            for (int p = 0; p < 8; ++p) {
                float4 rv = R4[p * 32 + j];
                acc[p] += w.x * rv.x + w.y * rv.y + w.z * rv.z + w.w * rv.w;
            }
        }
#pragma unroll
        for (int p = 0; p < 8; ++p)
            ws[WS_QP + (br0 + p) * EE + tid] = acc[p];
        return;
    }
    blk -= NB_QP;

    if (blk < NB_KT) {                 // ---- k proj, 16 rows -> kt[b,e,s]
        int s16 = blk * 16;
#pragma unroll
        for (int p = 0; p < 16; ++p) rows[p * EE + tid] = key[(s16 + p) * EE + tid];
        __syncthreads();
        float acc[16];
        float bv = bk[tid];
#pragma unroll
        for (int p = 0; p < 16; ++p) acc[p] = bv;
        const float4* W4 = (const float4*)(Wk + tid * EE);
        const float4* R4 = (const float4*)rows;
#pragma unroll
        for (int j = 0; j < EE / 4; ++j) {
            float4 w = W4[j];
#pragma unroll
            for (int p = 0; p < 16; ++p) {
                float4 rv = R4[p * 32 + j];
                acc[p] += w.x * rv.x + w.y * rv.y + w.z * rv.z + w.w * rv.w;
            }
        }
        int b = s16 / SS, s0 = s16 % SS;
        float4* dst = (float4*)(ws + WS_KT + (b * EE + tid) * SS + s0);
#pragma unroll
        for (int q4 = 0; q4 < 4; ++q4) {
            float4 v; v.x = acc[q4*4]; v.y = acc[q4*4+1]; v.z = acc[q4*4+2]; v.w = acc[q4*4+3];
            dst[q4] = v;
        }
        return;
    }
    blk -= NB_KT;

    {                                  // ---- Wo transpose -> wot[j][n]
        int gid = blk * 128 + tid;
        if (gid < HD * NHH) {
            int n = gid & 127, j = gid >> 7;
            ws[WS_WOT + gid] = Wo[n * HD + j];
        }
    }
}

// ======== K2: scores + masked softmax + PV + out-GEMV, 2 r per block
// phase B: lane = d (33 active), wave = 64-s strip; no shfl reductions.
__global__ __launch_bounds__(512) void fused_kernel(
    const float* __restrict__ qp, const float* __restrict__ kt,
    const float* __restrict__ value, const float* __restrict__ maskp,
    const float* __restrict__ tt, const float* __restrict__ qt,
    const float* __restrict__ sa, const float* __restrict__ wot,
    const float* __restrict__ bo, float* __restrict__ out)
{
    __shared__ float s_q[2][EE];           // 1 KB
    __shared__ float s_tt[SS];             // 2 KB
    __shared__ float s_sa[DD];
    // s_pool: phase A/B = E[rr][s][h] (4096 f); epilogue = redp/redw/redv
    __shared__ float s_pool[4488];         // 17.95 KB
    __shared__ float s_x[2][HD];           // 1 KB
    __shared__ float s_part[4][NHH];       // 2 KB

    int blk = blockIdx.x;
    int b  = blk >> 6;                     // 64 r-tiles per batch
    int r0 = (blk & 63) * 2;
    int tid = threadIdx.x;

    if (tid < 256) s_q[tid >> 7][tid & 127] =
        qp[(b * RR + r0 + (tid >> 7)) * EE + (tid & 127)];
    s_tt[tid] = tt[b * SS + tid];
    if (tid < DD) s_sa[tid] = sa[tid];
    __syncthreads();

    // ---- phase A: E[rr][s][h] = exp(score) into s_pool
    {
        int h = tid >> 7, sq = tid & 127;          // 4 s per thread: s = sq+128*si
        const float* kb = kt + (b * EE + h * EKK) * SS;
        float a0[4] = {0,0,0,0}, a1[4] = {0,0,0,0};
#pragma unroll
        for (int e = 0; e < EKK; ++e) {
            float q0 = s_q[0][h * EKK + e];
            float q1 = s_q[1][h * EKK + e];
            const float* krow = kb + e * SS + sq;
#pragma unroll
            for (int si = 0; si < 4; ++si) {
                float kv = krow[si * 128];
                a0[si] += q0 * kv;
                a1[si] += q1 * kv;
            }
        }
        const float scale = 0.17677669529663687f;  // 1/sqrt(32)
#pragma unroll
        for (int si = 0; si < 4; ++si) {
            int s = sq + 128 * si;
            s_pool[s * 4 + h]            = __expf(a0[si] * scale);
            s_pool[(SS + s) * 4 + h]     = __expf(a1[si] * scale);
        }
    }
    __syncthreads();

    // ---- phase B: lane=d, wave=s-strip; serial accumulation, no shfl
    int wv = tid >> 6, lane = tid & 63;
    float ps0[HH] = {0,0,0,0}, ps1[HH] = {0,0,0,0};
    float ws0[HH] = {0,0,0,0}, ws1[HH] = {0,0,0,0};
    float vsum = 0.f;

    if (lane < DD) {
        float qtr0 = qt[r0], qtr1 = qt[r0 + 1];
        float sad = s_sa[lane];
        float lo0 = qtr0 - sad, hi0 = qtr0 + sad;
        float lo1 = qtr1 - sad, hi1 = qtr1 + sad;

        const float* vp = value + (size_t)(b * SS + wv * 64) * DD + lane;
        const float* mp = maskp + (size_t)(b * SS + wv * 64) * DD + lane;

        for (int i4 = 0; i4 < 16; ++i4) {
            float4 t4 = *(const float4*)&s_tt[wv * 64 + i4 * 4];
            float tvs[4] = {t4.x, t4.y, t4.z, t4.w};
#pragma unroll
            for (int u = 0; u < 4; ++u) {
                int i = i4 * 4 + u;
                int s = wv * 64 + i;
                float vv = vp[i * DD];
                float mv = mp[i * DD];
                float tv = tvs[u];
                vsum += vv;
                bool mb = (mv != 0.f);
                bool k0 = mb & (tv >= lo0) & (tv <= hi0);
                bool k1 = mb & (tv >= lo1) & (tv <= hi1);
                float4 e0 = *(const float4*)&s_pool[s * 4];         // rr=0
                float4 e1 = *(const float4*)&s_pool[(SS + s) * 4];  // rr=1
                float ev0[4] = {e0.x, e0.y, e0.z, e0.w};
                float ev1[4] = {e1.x, e1.y, e1.z, e1.w};
#pragma unroll
                for (int h = 0; h < HH; ++h) {
                    float p0 = k0 ? ev0[h] : 0.f;
                    ps0[h] += p0; ws0[h] += p0 * vv;
                    float p1 = k1 ? ev1[h] : 0.f;
                    ps1[h] += p1; ws1[h] += p1 * vv;
                }
            }
        }
    }
    __syncthreads();   // all E reads done; s_pool now reusable

    float* s_redp = s_pool;            // [8][2][4][33] = 2112
    float* s_redw = s_pool + 2112;     // [8][2][4][33] = 2112
    float* s_redv = s_pool + 4224;     // [8][33]       = 264

    if (lane < DD) {
#pragma unroll
        for (int h = 0; h < HH; ++h) {
            s_redp[((wv * 2 + 0) * 4 + h) * DD + lane] = ps0[h];
            s_redp[((wv * 2 + 1) * 4 + h) * DD + lane] = ps1[h];
            s_redw[((wv * 2 + 0) * 4 + h) * DD + lane] = ws0[h];
            s_redw[((wv * 2 + 1) * 4 + h) * DD + lane] = ws1[h];
        }
        s_redv[wv * DD + lane] = vsum;
    }
    __syncthreads();

    if (tid < 2 * HH * DD) {           // 264 threads: (rr, h, d)
        int rr  = tid / (HH * DD);
        int rem = tid - rr * (HH * DD);
        int h   = rem / DD;
        int d   = rem - h * DD;
        float p = 0.f, w = 0.f;
#pragma unroll
        for (int k = 0; k < 8; ++k) {
            p += s_redp[((k * 2 + rr) * 4 + h) * DD + d];
            w += s_redw[((k * 2 + rr) * 4 + h) * DD + d];
        }
        float xv;
        if (p > 0.f) xv = w / p;
        else {
            float va = 0.f;
#pragma unroll
            for (int k = 0; k < 8; ++k) va += s_redv[k * DD + d];
            xv = va * (1.0f / SS);
        }
        s_x[rr][h * DD + d] = xv;
    }
    __syncthreads();

    // ---- phase C: out GEMV for both r (j split 2x66)
    {
        int g2 = tid >> 7;                 // 0..3 : rr = g2>>1, jg = g2&1
        int rr = g2 >> 1, jg = g2 & 1;
        int n = tid & 127;
        float acc = 0.f;
#pragma unroll
        for (int j = 0; j < 66; ++j)
            acc += s_x[rr][jg * 66 + j] * wot[(jg * 66 + j) * NHH + n];
        s_part[g2][n] = acc;
    }
    __syncthreads();
    if (tid < 256) {
        int rr = tid >> 7, n = tid & 127;
        out[(b * RR + r0 + rr) * NHH + n] =
            bo[n] + s_part[rr * 2][n] + s_part[rr * 2 + 1][n];
    }
}

// ================================================================== launch
extern "C" void kernel_launch(void* const* d_in, const int* in_sizes, int n_in,
                              void* d_out, int out_size, void* d_ws, size_t ws_size,
                              hipStream_t stream) {
    const float* query   = (const float*)d_in[0];
    const float* key     = (const float*)d_in[1];
    const float* value   = (const float*)d_in[2];
    const float* mask    = (const float*)d_in[3];
    const float* qt      = (const float*)d_in[4];
    const float* tt      = (const float*)d_in[5];
    const float* stridev = (const float*)d_in[6];
    const float* Wq      = (const float*)d_in[7];
    const float* bq      = (const float*)d_in[8];
    const float* Wk      = (const float*)d_in[9];
    const float* bk      = (const float*)d_in[10];
    const float* Wr      = (const float*)d_in[11];
    const float* brv     = (const float*)d_in[12];
    const float* Wo      = (const float*)d_in[13];
    const float* bo      = (const float*)d_in[14];

    float* out = (float*)d_out;               // 131072 out + 33 sa
    float* ws  = (float*)d_ws;

    prep_kernel<<<NB_PREP, 128, 0, stream>>>(
        query, key, stridev, Wq, bq, Wk, bk, Wr, brv, Wo,
        ws, out + BB * RR * NHH);
    fused_kernel<<<BB * 64, 512, 0, stream>>>(
        ws + WS_QP, ws + WS_KT, value, mask,
        tt, qt, ws + WS_SA, ws + WS_WOT, bo, out);
}

// Round 8
// 39.886 us; speedup vs baseline: 1.3861x; 1.0033x over previous
//
#include <hip/hip_runtime.h>

#define BB   8
#define RR   128
#define SS   512
#define DD   33
#define EE   128
#define HH   4
#define EKK  32
#define NHH  128
#define HD   (HH*DD)      // 132

// ---- workspace layout (float offsets) ----
#define WS_QP   0                         // B*R*E  = 131072 (row-major)
#define WS_KT   (BB*RR*EE)                // B*E*S  = 524288 (transposed)
#define WS_WOT  (WS_KT + BB*EE*SS)        // HD*NH  = 16896

#define NB_KP   512                       // 8 key rows per block
#define NB_QP2  128                       // 8 query rows per block
#define NB_WOT2 66
#define NB_PREP (NB_KP + NB_QP2 + NB_WOT2)

// ============================================================== K1: prep
__global__ __launch_bounds__(256) void prep_kernel(
    const float* __restrict__ query, const float* __restrict__ key,
    const float* __restrict__ Wq, const float* __restrict__ bq,
    const float* __restrict__ Wk, const float* __restrict__ bk,
    const float* __restrict__ Wo, float* __restrict__ ws)
{
    __shared__ float rows[8 * EE];     // 4 KB
    int blk = blockIdx.x, tid = threadIdx.x;

    if (blk < NB_KP) {                 // ---- k proj, 8 rows -> kt[b,e,s]
        int s8 = blk * 8;
#pragma unroll
        for (int i = 0; i < 4; ++i) rows[i * 256 + tid] = key[s8 * EE + i * 256 + tid];
        __syncthreads();
        int g = tid >> 7, e = tid & 127;      // g: row-quad 0/1
        float acc[4];
        float bv = bk[e];
#pragma unroll
        for (int p = 0; p < 4; ++p) acc[p] = bv;
        const float4* W4 = (const float4*)(Wk + e * EE);
        const float4* R4 = (const float4*)rows;
#pragma unroll
        for (int j = 0; j < EE / 4; ++j) {
            float4 w = W4[j];
#pragma unroll
            for (int p = 0; p < 4; ++p) {
                float4 rv = R4[(g * 4 + p) * 32 + j];
                acc[p] += w.x * rv.x + w.y * rv.y + w.z * rv.z + w.w * rv.w;
            }
        }
        int b = s8 / SS, s0 = s8 % SS;
        float4 v; v.x = acc[0]; v.y = acc[1]; v.z = acc[2]; v.w = acc[3];
        *(float4*)(ws + WS_KT + (b * EE + e) * SS + s0 + g * 4) = v;
        return;
    }
    blk -= NB_KP;

    if (blk < NB_QP2) {                // ---- q proj, 8 rows -> qp[b,r,e]
        int br0 = blk * 8;
#pragma unroll
        for (int i = 0; i < 4; ++i) rows[i * 256 + tid] = query[br0 * EE + i * 256 + tid];
        __syncthreads();
        int g = tid >> 7, e = tid & 127;
        float acc[4];
        float bv = bq[e];
#pragma unroll
        for (int p = 0; p < 4; ++p) acc[p] = bv;
        const float4* W4 = (const float4*)(Wq + e * EE);
        const float4* R4 = (const float4*)rows;
#pragma unroll
        for (int j = 0; j < EE / 4; ++j) {
            float4 w = W4[j];
#pragma unroll
            for (int p = 0; p < 4; ++p) {
                float4 rv = R4[(g * 4 + p) * 32 + j];
                acc[p] += w.x * rv.x + w.y * rv.y + w.z * rv.z + w.w * rv.w;
            }
        }
#pragma unroll
        for (int p = 0; p < 4; ++p)
            ws[WS_QP + (br0 + g * 4 + p) * EE + e] = acc[p];
        return;
    }
    blk -= NB_QP2;

    {                                  // ---- Wo transpose -> wot[j][n]
        int gid = blk * 256 + tid;
        if (gid < HD * NHH) {
            int n = gid & 127, j = gid >> 7;
            ws[WS_WOT + gid] = Wo[n * HD + j];
        }
    }
}

// ================= K2: sa + scores + masked softmax + PV + GEMV, 2 r/block
// pool union: phase A/B = E[rr][h][s] (4096 f); epilogue = reductions (4488 f)
#define POOL_REDP 0        // [8][2][4][32]
#define POOL_REDW 2048     // [8][2][4][32]
#define POOL_REDV 4096     // [8][32]
#define POOL_R32P 4352     // [8][2][4]
#define POOL_R32W 4416     // [8][2][4]
#define POOL_R32V 4480     // [8]
#define EIDX(rr,h,s) (((rr)*HH+(h))*SS + (s))

__global__ __launch_bounds__(512) void fused_kernel(
    const float* __restrict__ qp, const float* __restrict__ kt,
    const float* __restrict__ value, const float* __restrict__ maskp,
    const float* __restrict__ tt, const float* __restrict__ qt,
    const float* __restrict__ stridev, const float* __restrict__ Wr,
    const float* __restrict__ brv, const float* __restrict__ wot,
    const float* __restrict__ bo, float* __restrict__ out)
{
    __shared__ float s_q[2][EE];           // 1 KB
    __shared__ float s_tt[SS];             // 2 KB
    __shared__ float s_sa[DD + 3];
    __shared__ float s_pool[4488];         // 17.95 KB
    __shared__ float s_x[2][HD];
    __shared__ float s_part[4][NHH];       // 2 KB

    int blk = blockIdx.x;
    int b  = blk >> 6;
    int r0 = (blk & 63) * 2;
    int tid = threadIdx.x;

    if (tid < 256) s_q[tid >> 7][tid & 127] =
        qp[(b * RR + r0 + (tid >> 7)) * EE + (tid & 127)];
    s_tt[tid] = tt[b * SS + tid];
    if (tid < DD) {                        // sa computed per-block (cheap)
        float acc = brv[tid];
#pragma unroll
        for (int j = 0; j < DD; ++j) acc += stridev[j] * Wr[tid * DD + j];
        float sv = 1.0f / (1.0f + __expf(-acc));
        s_sa[tid] = sv;
        if (blk == 0) out[BB * RR * NHH + tid] = sv;   // sa output tail
    }
    __syncthreads();

    // ---- phase A: E[rr][h][s] = exp(score); float4 loads, b128 writes
    {
        int h = tid >> 7, sq = tid & 127;          // s = 4sq .. 4sq+3
        const float* kb = kt + (b * EE + h * EKK) * SS;
        float4 a0 = {0,0,0,0}, a1 = {0,0,0,0};
#pragma unroll
        for (int e = 0; e < EKK; ++e) {
            float4 kv = ((const float4*)(kb + e * SS))[sq];
            float q0 = s_q[0][h * EKK + e];
            float q1 = s_q[1][h * EKK + e];
            a0.x += q0 * kv.x; a0.y += q0 * kv.y; a0.z += q0 * kv.z; a0.w += q0 * kv.w;
            a1.x += q1 * kv.x; a1.y += q1 * kv.y; a1.z += q1 * kv.z; a1.w += q1 * kv.w;
        }
        const float scale = 0.17677669529663687f;  // 1/sqrt(32)
        float4 e0, e1;
        e0.x = __expf(a0.x * scale); e0.y = __expf(a0.y * scale);
        e0.z = __expf(a0.z * scale); e0.w = __expf(a0.w * scale);
        e1.x = __expf(a1.x * scale); e1.y = __expf(a1.y * scale);
        e1.z = __expf(a1.z * scale); e1.w = __expf(a1.w * scale);
        ((float4*)&s_pool[EIDX(0, h, 0)])[sq] = e0;
        ((float4*)&s_pool[EIDX(1, h, 0)])[sq] = e1;
    }
    __syncthreads();

    // ---- phase B: lane = (s-parity, d<32); all 64 lanes active
    int wv = tid >> 6, lane = tid & 63;
    int sp = lane >> 5, d = lane & 31;
    int s0 = wv * 64;
    float qtr0 = qt[r0], qtr1 = qt[r0 + 1];

    float ps0[HH] = {0,0,0,0}, ps1[HH] = {0,0,0,0};
    float ws0_[HH] = {0,0,0,0}, ws1_[HH] = {0,0,0,0};
    float vsum = 0.f;
    {
        float sad = s_sa[d];
        float lo0 = qtr0 - sad, hi0 = qtr0 + sad;
        float lo1 = qtr1 - sad, hi1 = qtr1 + sad;
        const float* vp = value + (size_t)(b * SS + s0 + sp) * DD + d;
        const float* mp = maskp + (size_t)(b * SS + s0 + sp) * DD + d;
#pragma unroll 4
        for (int i = 0; i < 32; ++i) {
            int s = s0 + 2 * i + sp;
            float vv = vp[i * 2 * DD];
            float mv = mp[i * 2 * DD];
            float tv = s_tt[s];
            bool mb = (mv != 0.f);
            bool k0 = mb & (tv >= lo0) & (tv <= hi0);
            bool k1 = mb & (tv >= lo1) & (tv <= hi1);
            vsum += vv;
#pragma unroll
            for (int h = 0; h < HH; ++h) {
                float e0 = s_pool[EIDX(0, h, s)];
                float e1 = s_pool[EIDX(1, h, s)];
                float p0 = k0 ? e0 : 0.f;
                float p1 = k1 ? e1 : 0.f;
                ps0[h] += p0; ws0_[h] += p0 * vv;
                ps1[h] += p1; ws1_[h] += p1 * vv;
            }
        }
        // combine s-parity pairs (lane l <-> l+32)
#pragma unroll
        for (int h = 0; h < HH; ++h) {
            ps0[h] += __shfl_xor(ps0[h], 32); ws0_[h] += __shfl_xor(ws0_[h], 32);
            ps1[h] += __shfl_xor(ps1[h], 32); ws1_[h] += __shfl_xor(ws1_[h], 32);
        }
        vsum += __shfl_xor(vsum, 32);
    }

    // ---- d = 32 tail: lane = rr*32 + h*8 + j, each j covers 8 s
    float tps = 0.f, tws = 0.f, tvs = 0.f;
    {
        int trr = lane >> 5, th = (lane >> 3) & 3, tj = lane & 7;
        float sad = s_sa[32];
        float lo = (trr ? qtr1 : qtr0) - sad, hi = (trr ? qtr1 : qtr0) + sad;
#pragma unroll
        for (int i = 0; i < 8; ++i) {
            int s = s0 + tj * 8 + i;
            float vv = value[(size_t)(b * SS + s) * DD + 32];
            float mv = maskp[(size_t)(b * SS + s) * DD + 32];
            float tv = s_tt[s];
            bool k = (mv != 0.f) & (tv >= lo) & (tv <= hi);
            float e = s_pool[EIDX(trr, th, s)];
            float p = k ? e : 0.f;
            tps += p; tws += p * vv; tvs += vv;
        }
#pragma unroll
        for (int off = 1; off < 8; off <<= 1) {
            tps += __shfl_xor(tps, off);
            tws += __shfl_xor(tws, off);
            tvs += __shfl_xor(tvs, off);
        }
    }
    __syncthreads();   // all E reads done; pool reusable

    if (lane < 32) {
#pragma unroll
        for (int h = 0; h < HH; ++h) {
            s_pool[POOL_REDP + ((wv * 2 + 0) * HH + h) * 32 + lane] = ps0[h];
            s_pool[POOL_REDP + ((wv * 2 + 1) * HH + h) * 32 + lane] = ps1[h];
            s_pool[POOL_REDW + ((wv * 2 + 0) * HH + h) * 32 + lane] = ws0_[h];
            s_pool[POOL_REDW + ((wv * 2 + 1) * HH + h) * 32 + lane] = ws1_[h];
        }
        s_pool[POOL_REDV + wv * 32 + lane] = vsum;
    }
    if ((lane & 7) == 0) {
        int trr = lane >> 5, th = (lane >> 3) & 3;
        s_pool[POOL_R32P + (wv * 2 + trr) * HH + th] = tps;
        s_pool[POOL_R32W + (wv * 2 + trr) * HH + th] = tws;
        if (lane == 0) s_pool[POOL_R32V + wv] = tvs;
    }
    __syncthreads();

    // ---- assemble x
    if (tid < 256) {
        int rr = tid >> 7, hd = tid & 127, h = hd >> 5, dd = hd & 31;
        float p = 0.f, w = 0.f;
#pragma unroll
        for (int k = 0; k < 8; ++k) {
            p += s_pool[POOL_REDP + ((k * 2 + rr) * HH + h) * 32 + dd];
            w += s_pool[POOL_REDW + ((k * 2 + rr) * HH + h) * 32 + dd];
        }
        float xv;
        if (p > 0.f) xv = w / p;
        else {
            float va = 0.f;
#pragma unroll
            for (int k = 0; k < 8; ++k) va += s_pool[POOL_REDV + k * 32 + dd];
            xv = va * (1.0f / SS);
        }
        s_x[rr][h * DD + dd] = xv;
    } else if (tid < 264) {
        int t = tid - 256, rr = t >> 2, h = t & 3;
        float p = 0.f, w = 0.f;
#pragma unroll
        for (int k = 0; k < 8; ++k) {
            p += s_pool[POOL_R32P + (k * 2 + rr) * HH + h];
            w += s_pool[POOL_R32W + (k * 2 + rr) * HH + h];
        }
        float xv;
        if (p > 0.f) xv = w / p;
        else {
            float va = 0.f;
#pragma unroll
            for (int k = 0; k < 8; ++k) va += s_pool[POOL_R32V + k];
            xv = va * (1.0f / SS);
        }
        s_x[rr][h * DD + 32] = xv;
    }
    __syncthreads();

    // ---- phase C: out GEMV for both r (j split 2x66)
    {
        int g2 = tid >> 7;                 // rr = g2>>1, jg = g2&1
        int rr = g2 >> 1, jg = g2 & 1;
        int n = tid & 127;
        float acc = 0.f;
#pragma unroll
        for (int j = 0; j < 66; ++j)
            acc += s_x[rr][jg * 66 + j] * wot[(jg * 66 + j) * NHH + n];
        s_part[g2][n] = acc;
    }
    __syncthreads();
    if (tid < 256) {
        int rr = tid >> 7, n = tid & 127;
        out[(b * RR + r0 + rr) * NHH + n] =
            bo[n] + s_part[rr * 2][n] + s_part[rr * 2 + 1][n];
    }
}

// ================================================================== launch
extern "C" void kernel_launch(void* const* d_in, const int* in_sizes, int n_in,
                              void* d_out, int out_size, void* d_ws, size_t ws_size,
                              hipStream_t stream) {
    const float* query   = (const float*)d_in[0];
    const float* key     = (const float*)d_in[1];
    const float* value   = (const float*)d_in[2];
    const float* mask    = (const float*)d_in[3];
    const float* qt      = (const float*)d_in[4];
    const float* tt      = (const float*)d_in[5];
    const float* stridev = (const float*)d_in[6];
    const float* Wq      = (const float*)d_in[7];
    const float* bq      = (const float*)d_in[8];
    const float* Wk      = (const float*)d_in[9];
    const float* bk      = (const float*)d_in[10];
    const float* Wr      = (const float*)d_in[11];
    const float* brv     = (const float*)d_in[12];
    const float* Wo      = (const float*)d_in[13];
    const float* bo      = (const float*)d_in[14];

    float* out = (float*)d_out;               // 131072 out + 33 sa
    float* ws  = (float*)d_ws;

    prep_kernel<<<NB_PREP, 256, 0, stream>>>(
        query, key, Wq, bq, Wk, bk, Wo, ws);
    fused_kernel<<<BB * 64, 512, 0, stream>>>(
        ws + WS_QP, ws + WS_KT, value, mask, tt, qt,
        stridev, Wr, brv, ws + WS_WOT, bo, out);
}

// Round 9
// 39.792 us; speedup vs baseline: 1.3894x; 1.0024x over previous
//
#include <hip/hip_runtime.h>
#include <hip/hip_cooperative_groups.h>

namespace cg = cooperative_groups;

#define BB   8
#define RR   128
#define SS   512
#define DD   33
#define EE   128
#define HH   4
#define EKK  32
#define NHH  128
#define HD   (HH*DD)      // 132

// ---- workspace layout (float offsets) ----
#define WS_KT   0                          // B*E*S = 524288 (transposed k-proj)
#define WS_WOT  (BB*EE*SS)                 // HD*NH = 16896
#define WS_QP   (WS_WOT + HD*NHH)          // B*R*E = 131072 (fallback path only)

// pool union: phase A/B = E[rr][h][s] (4096 f); epilogue = reductions
#define POOL_REDP 0        // [8][2][4][32]
#define POOL_REDW 2048     // [8][2][4][32]
#define POOL_REDV 4096     // [8][32]
#define POOL_R32P 4352     // [8][2][4]
#define POOL_R32W 4416     // [8][2][4]
#define POOL_R32V 4480     // [8]
#define EIDX(rr,h,s) (((rr)*HH+(h))*SS + (s))

// =========================================================================
// Cooperative single-launch kernel: 512 blocks x 512 threads, 2 blocks/CU
// =========================================================================
__global__ __launch_bounds__(512, 4) void mega_kernel(
    const float* __restrict__ query, const float* __restrict__ key,
    const float* __restrict__ value, const float* __restrict__ maskp,
    const float* __restrict__ qt, const float* __restrict__ tt,
    const float* __restrict__ stridev,
    const float* __restrict__ Wq, const float* __restrict__ bq,
    const float* __restrict__ Wk, const float* __restrict__ bk,
    const float* __restrict__ Wr, const float* __restrict__ brv,
    const float* __restrict__ Wo, const float* __restrict__ bo,
    float* __restrict__ ws, float* __restrict__ out)
{
    __shared__ float s_q[2][EE];           // 1 KB
    __shared__ float s_tt[SS];             // 2 KB
    __shared__ float s_sa[DD + 3];
    __shared__ float s_pool[4488];         // 17.95 KB
    __shared__ float s_x[2][HD];
    __shared__ float s_part[4][NHH];       // 2 KB
    __shared__ float s_rows[8 * EE];       // 4 KB (staging)

    int bid = blockIdx.x, tid = threadIdx.x;
    int b  = bid >> 6;
    int r0 = (bid & 63) * 2;

    // ================= stage 0: projections =================
    // 0a: stage 8 key rows (this block owns rows s8..s8+7 of flat b*S+s)
    int s8 = bid * 8;
    s_rows[tid]       = key[s8 * EE + tid];
    s_rows[tid + 512] = key[s8 * EE + 512 + tid];
    // concurrent: tt stage, sa compute, wot transpose (disjoint LDS/global)
    s_tt[tid] = tt[b * SS + tid];
    if (tid < DD) {
        float acc = brv[tid];
#pragma unroll
        for (int j = 0; j < DD; ++j) acc += stridev[j] * Wr[tid * DD + j];
        float sv = 1.0f / (1.0f + __expf(-acc));
        s_sa[tid] = sv;
        if (bid == 0) out[BB * RR * NHH + tid] = sv;    // sa output tail
    }
    if (bid < 66) {
        int gid = bid * 256 + tid;
        if (gid < HD * NHH) {
            int n = gid & 127, j = gid >> 7;
            ws[WS_WOT + gid] = Wo[n * HD + j];
        }
    }
    __syncthreads();

    // 0a cont: k-proj 8 rows -> kt[b][e][s], each thread 2 rows
    {
        int g = tid >> 7, e = tid & 127;       // g in 0..3 -> rows 2g,2g+1
        float acc0 = bk[e], acc1 = acc0;
        const float4* W4 = (const float4*)(Wk + e * EE);
        const float4* R4 = (const float4*)s_rows;
#pragma unroll
        for (int j = 0; j < EE / 4; ++j) {
            float4 w  = W4[j];
            float4 r0v = R4[(g * 2 + 0) * 32 + j];
            float4 r1v = R4[(g * 2 + 1) * 32 + j];
            acc0 += w.x * r0v.x + w.y * r0v.y + w.z * r0v.z + w.w * r0v.w;
            acc1 += w.x * r1v.x + w.y * r1v.y + w.z * r1v.z + w.w * r1v.w;
        }
        int kb = s8 / SS, s0 = s8 % SS;
        float2 v; v.x = acc0; v.y = acc1;
        *(float2*)(ws + WS_KT + (kb * EE + e) * SS + s0 + g * 2) = v;
    }
    __syncthreads();

    // 0b: q-proj for this block's own 2 rows, straight into LDS
    if (tid < 256) s_rows[tid] = query[(b * RR + r0 + (tid >> 7)) * EE + (tid & 127)];
    __syncthreads();
    if (tid < 256) {
        int rr = tid >> 7, e = tid & 127;
        float acc = bq[e];
        const float4* W4 = (const float4*)(Wq + e * EE);
        const float4* R4 = (const float4*)(s_rows + rr * EE);
#pragma unroll
        for (int j = 0; j < EE / 4; ++j) {
            float4 w = W4[j]; float4 rv = R4[j];
            acc += w.x * rv.x + w.y * rv.y + w.z * rv.z + w.w * rv.w;
        }
        s_q[rr][e] = acc;
    }

    // ================= grid-wide sync: kt/wot now visible =================
    cg::this_grid().sync();

    const float* kt  = ws + WS_KT;
    const float* wot = ws + WS_WOT;

    // ---- phase A: E[rr][h][s] = exp(score); float4 loads, b128 writes
    {
        int h = tid >> 7, sq = tid & 127;          // s = 4sq .. 4sq+3
        const float* kb = kt + (b * EE + h * EKK) * SS;
        float4 a0 = {0,0,0,0}, a1 = {0,0,0,0};
#pragma unroll
        for (int e = 0; e < EKK; ++e) {
            float4 kv = ((const float4*)(kb + e * SS))[sq];
            float q0 = s_q[0][h * EKK + e];
            float q1 = s_q[1][h * EKK + e];
            a0.x += q0 * kv.x; a0.y += q0 * kv.y; a0.z += q0 * kv.z; a0.w += q0 * kv.w;
            a1.x += q1 * kv.x; a1.y += q1 * kv.y; a1.z += q1 * kv.z; a1.w += q1 * kv.w;
        }
        const float scale = 0.17677669529663687f;  // 1/sqrt(32)
        float4 e0, e1;
        e0.x = __expf(a0.x * scale); e0.y = __expf(a0.y * scale);
        e0.z = __expf(a0.z * scale); e0.w = __expf(a0.w * scale);
        e1.x = __expf(a1.x * scale); e1.y = __expf(a1.y * scale);
        e1.z = __expf(a1.z * scale); e1.w = __expf(a1.w * scale);
        ((float4*)&s_pool[EIDX(0, h, 0)])[sq] = e0;
        ((float4*)&s_pool[EIDX(1, h, 0)])[sq] = e1;
    }
    __syncthreads();

    // ---- phase B: lane = (s-parity, d<32); all 64 lanes active
    int wv = tid >> 6, lane = tid & 63;
    int sp = lane >> 5, d = lane & 31;
    int s0 = wv * 64;
    float qtr0 = qt[r0], qtr1 = qt[r0 + 1];

    float ps0[HH] = {0,0,0,0}, ps1[HH] = {0,0,0,0};
    float ws0_[HH] = {0,0,0,0}, ws1_[HH] = {0,0,0,0};
    float vsum = 0.f;
    {
        float sad = s_sa[d];
        float lo0 = qtr0 - sad, hi0 = qtr0 + sad;
        float lo1 = qtr1 - sad, hi1 = qtr1 + sad;
        const float* vp = value + (size_t)(b * SS + s0 + sp) * DD + d;
        const float* mp = maskp + (size_t)(b * SS + s0 + sp) * DD + d;
#pragma unroll 4
        for (int i = 0; i < 32; ++i) {
            int s = s0 + 2 * i + sp;
            float vv = vp[i * 2 * DD];
            float mv = mp[i * 2 * DD];
            float tv = s_tt[s];
            bool mb = (mv != 0.f);
            bool k0 = mb & (tv >= lo0) & (tv <= hi0);
            bool k1 = mb & (tv >= lo1) & (tv <= hi1);
            vsum += vv;
#pragma unroll
            for (int h = 0; h < HH; ++h) {
                float e0 = s_pool[EIDX(0, h, s)];
                float e1 = s_pool[EIDX(1, h, s)];
                float p0 = k0 ? e0 : 0.f;
                float p1 = k1 ? e1 : 0.f;
                ps0[h] += p0; ws0_[h] += p0 * vv;
                ps1[h] += p1; ws1_[h] += p1 * vv;
            }
        }
#pragma unroll
        for (int h = 0; h < HH; ++h) {
            ps0[h] += __shfl_xor(ps0[h], 32); ws0_[h] += __shfl_xor(ws0_[h], 32);
            ps1[h] += __shfl_xor(ps1[h], 32); ws1_[h] += __shfl_xor(ws1_[h], 32);
        }
        vsum += __shfl_xor(vsum, 32);
    }

    // ---- d = 32 tail
    float tps = 0.f, tws = 0.f, tvs = 0.f;
    {
        int trr = lane >> 5, th = (lane >> 3) & 3, tj = lane & 7;
        float sad = s_sa[32];
        float lo = (trr ? qtr1 : qtr0) - sad, hi = (trr ? qtr1 : qtr0) + sad;
#pragma unroll
        for (int i = 0; i < 8; ++i) {
            int s = s0 + tj * 8 + i;
            float vv = value[(size_t)(b * SS + s) * DD + 32];
            float mv = maskp[(size_t)(b * SS + s) * DD + 32];
            float tv = s_tt[s];
            bool k = (mv != 0.f) & (tv >= lo) & (tv <= hi);
            float e = s_pool[EIDX(trr, th, s)];
            float p = k ? e : 0.f;
            tps += p; tws += p * vv; tvs += vv;
        }
#pragma unroll
        for (int off = 1; off < 8; off <<= 1) {
            tps += __shfl_xor(tps, off);
            tws += __shfl_xor(tws, off);
            tvs += __shfl_xor(tvs, off);
        }
    }
    __syncthreads();   // all E reads done; pool reusable

    if (lane < 32) {
#pragma unroll
        for (int h = 0; h < HH; ++h) {
            s_pool[POOL_REDP + ((wv * 2 + 0) * HH + h) * 32 + lane] = ps0[h];
            s_pool[POOL_REDP + ((wv * 2 + 1) * HH + h) * 32 + lane] = ps1[h];
            s_pool[POOL_REDW + ((wv * 2 + 0) * HH + h) * 32 + lane] = ws0_[h];
            s_pool[POOL_REDW + ((wv * 2 + 1) * HH + h) * 32 + lane] = ws1_[h];
        }
        s_pool[POOL_REDV + wv * 32 + lane] = vsum;
    }
    if ((lane & 7) == 0) {
        int trr = lane >> 5, th = (lane >> 3) & 3;
        s_pool[POOL_R32P + (wv * 2 + trr) * HH + th] = tps;
        s_pool[POOL_R32W + (wv * 2 + trr) * HH + th] = tws;
        if (lane == 0) s_pool[POOL_R32V + wv] = tvs;
    }
    __syncthreads();

    // ---- assemble x
    if (tid < 256) {
        int rr = tid >> 7, hd = tid & 127, h = hd >> 5, dd = hd & 31;
        float p = 0.f, w = 0.f;
#pragma unroll
        for (int k = 0; k < 8; ++k) {
            p += s_pool[POOL_REDP + ((k * 2 + rr) * HH + h) * 32 + dd];
            w += s_pool[POOL_REDW + ((k * 2 + rr) * HH + h) * 32 + dd];
        }
        float xv;
        if (p > 0.f) xv = w / p;
        else {
            float va = 0.f;
#pragma unroll
            for (int k = 0; k < 8; ++k) va += s_pool[POOL_REDV + k * 32 + dd];
            xv = va * (1.0f / SS);
        }
        s_x[rr][h * DD + dd] = xv;
    } else if (tid < 264) {
        int t = tid - 256, rr = t >> 2, h = t & 3;
        float p = 0.f, w = 0.f;
#pragma unroll
        for (int k = 0; k < 8; ++k) {
            p += s_pool[POOL_R32P + (k * 2 + rr) * HH + h];
            w += s_pool[POOL_R32W + (k * 2 + rr) * HH + h];
        }
        float xv;
        if (p > 0.f) xv = w / p;
        else {
            float va = 0.f;
#pragma unroll
            for (int k = 0; k < 8; ++k) va += s_pool[POOL_R32V + k];
            xv = va * (1.0f / SS);
        }
        s_x[rr][h * DD + 32] = xv;
    }
    __syncthreads();

    // ---- phase C: out GEMV for both r
    {
        int g2 = tid >> 7;
        int rr = g2 >> 1, jg = g2 & 1;
        int n = tid & 127;
        float acc = 0.f;
#pragma unroll
        for (int j = 0; j < 66; ++j)
            acc += s_x[rr][jg * 66 + j] * wot[(jg * 66 + j) * NHH + n];
        s_part[g2][n] = acc;
    }
    __syncthreads();
    if (tid < 256) {
        int rr = tid >> 7, n = tid & 127;
        out[(b * RR + r0 + rr) * NHH + n] =
            bo[n] + s_part[rr * 2][n] + s_part[rr * 2 + 1][n];
    }
}

// =========================================================================
// Fallback path (round-8 two-kernel, verified) if coop can't co-reside
// =========================================================================
#define NB_KP   512
#define NB_QP2  128
#define NB_WOT2 66
#define NB_PREP (NB_KP + NB_QP2 + NB_WOT2)

__global__ __launch_bounds__(256) void prep_kernel(
    const float* __restrict__ query, const float* __restrict__ key,
    const float* __restrict__ Wq, const float* __restrict__ bq,
    const float* __restrict__ Wk, const float* __restrict__ bk,
    const float* __restrict__ Wo, float* __restrict__ ws)
{
    __shared__ float rows[8 * EE];
    int blk = blockIdx.x, tid = threadIdx.x;

    if (blk < NB_KP) {
        int s8 = blk * 8;
#pragma unroll
        for (int i = 0; i < 4; ++i) rows[i * 256 + tid] = key[s8 * EE + i * 256 + tid];
        __syncthreads();
        int g = tid >> 7, e = tid & 127;
        float acc[4];
        float bv = bk[e];
#pragma unroll
        for (int p = 0; p < 4; ++p) acc[p] = bv;
        const float4* W4 = (const float4*)(Wk + e * EE);
        const float4* R4 = (const float4*)rows;
#pragma unroll
        for (int j = 0; j < EE / 4; ++j) {
            float4 w = W4[j];
#pragma unroll
            for (int p = 0; p < 4; ++p) {
                float4 rv = R4[(g * 4 + p) * 32 + j];
                acc[p] += w.x * rv.x + w.y * rv.y + w.z * rv.z + w.w * rv.w;
            }
        }
        int b = s8 / SS, s0 = s8 % SS;
        float4 v; v.x = acc[0]; v.y = acc[1]; v.z = acc[2]; v.w = acc[3];
        *(float4*)(ws + WS_KT + (b * EE + e) * SS + s0 + g * 4) = v;
        return;
    }
    blk -= NB_KP;

    if (blk < NB_QP2) {
        int br0 = blk * 8;
#pragma unroll
        for (int i = 0; i < 4; ++i) rows[i * 256 + tid] = query[br0 * EE + i * 256 + tid];
        __syncthreads();
        int g = tid >> 7, e = tid & 127;
        float acc[4];
        float bv = bq[e];
#pragma unroll
        for (int p = 0; p < 4; ++p) acc[p] = bv;
        const float4* W4 = (const float4*)(Wq + e * EE);
        const float4* R4 = (const float4*)rows;
#pragma unroll
        for (int j = 0; j < EE / 4; ++j) {
            float4 w = W4[j];
#pragma unroll
            for (int p = 0; p < 4; ++p) {
                float4 rv = R4[(g * 4 + p) * 32 + j];
                acc[p] += w.x * rv.x + w.y * rv.y + w.z * rv.z + w.w * rv.w;
            }
        }
#pragma unroll
        for (int p = 0; p < 4; ++p)
            ws[WS_QP + (br0 + g * 4 + p) * EE + e] = acc[p];
        return;
    }
    blk -= NB_QP2;

    {
        int gid = blk * 256 + tid;
        if (gid < HD * NHH) {
            int n = gid & 127, j = gid >> 7;
            ws[WS_WOT + gid] = Wo[n * HD + j];
        }
    }
}

__global__ __launch_bounds__(512) void fused_kernel(
    const float* __restrict__ qp, const float* __restrict__ kt,
    const float* __restrict__ value, const float* __restrict__ maskp,
    const float* __restrict__ tt, const float* __restrict__ qt,
    const float* __restrict__ stridev, const float* __restrict__ Wr,
    const float* __restrict__ brv, const float* __restrict__ wot,
    const float* __restrict__ bo, float* __restrict__ out)
{
    __shared__ float s_q[2][EE];
    __shared__ float s_tt[SS];
    __shared__ float s_sa[DD + 3];
    __shared__ float s_pool[4488];
    __shared__ float s_x[2][HD];
    __shared__ float s_part[4][NHH];

    int blk = blockIdx.x;
    int b  = blk >> 6;
    int r0 = (blk & 63) * 2;
    int tid = threadIdx.x;

    if (tid < 256) s_q[tid >> 7][tid & 127] =
        qp[(b * RR + r0 + (tid >> 7)) * EE + (tid & 127)];
    s_tt[tid] = tt[b * SS + tid];
    if (tid < DD) {
        float acc = brv[tid];
#pragma unroll
        for (int j = 0; j < DD; ++j) acc += stridev[j] * Wr[tid * DD + j];
        float sv = 1.0f / (1.0f + __expf(-acc));
        s_sa[tid] = sv;
        if (blk == 0) out[BB * RR * NHH + tid] = sv;
    }
    __syncthreads();

    {
        int h = tid >> 7, sq = tid & 127;
        const float* kb = kt + (b * EE + h * EKK) * SS;
        float4 a0 = {0,0,0,0}, a1 = {0,0,0,0};
#pragma unroll
        for (int e = 0; e < EKK; ++e) {
            float4 kv = ((const float4*)(kb + e * SS))[sq];
            float q0 = s_q[0][h * EKK + e];
            float q1 = s_q[1][h * EKK + e];
            a0.x += q0 * kv.x; a0.y += q0 * kv.y; a0.z += q0 * kv.z; a0.w += q0 * kv.w;
            a1.x += q1 * kv.x; a1.y += q1 * kv.y; a1.z += q1 * kv.z; a1.w += q1 * kv.w;
        }
        const float scale = 0.17677669529663687f;
        float4 e0, e1;
        e0.x = __expf(a0.x * scale); e0.y = __expf(a0.y * scale);
        e0.z = __expf(a0.z * scale); e0.w = __expf(a0.w * scale);
        e1.x = __expf(a1.x * scale); e1.y = __expf(a1.y * scale);
        e1.z = __expf(a1.z * scale); e1.w = __expf(a1.w * scale);
        ((float4*)&s_pool[EIDX(0, h, 0)])[sq] = e0;
        ((float4*)&s_pool[EIDX(1, h, 0)])[sq] = e1;
    }
    __syncthreads();

    int wv = tid >> 6, lane = tid & 63;
    int sp = lane >> 5, d = lane & 31;
    int s0 = wv * 64;
    float qtr0 = qt[r0], qtr1 = qt[r0 + 1];

    float ps0[HH] = {0,0,0,0}, ps1[HH] = {0,0,0,0};
    float ws0_[HH] = {0,0,0,0}, ws1_[HH] = {0,0,0,0};
    float vsum = 0.f;
    {
        float sad = s_sa[d];
        float lo0 = qtr0 - sad, hi0 = qtr0 + sad;
        float lo1 = qtr1 - sad, hi1 = qtr1 + sad;
        const float* vp = value + (size_t)(b * SS + s0 + sp) * DD + d;
        const float* mp = maskp + (size_t)(b * SS + s0 + sp) * DD + d;
#pragma unroll 4
        for (int i = 0; i < 32; ++i) {
            int s = s0 + 2 * i + sp;
            float vv = vp[i * 2 * DD];
            float mv = mp[i * 2 * DD];
            float tv = s_tt[s];
            bool mb = (mv != 0.f);
            bool k0 = mb & (tv >= lo0) & (tv <= hi0);
            bool k1 = mb & (tv >= lo1) & (tv <= hi1);
            vsum += vv;
#pragma unroll
            for (int h = 0; h < HH; ++h) {
                float e0 = s_pool[EIDX(0, h, s)];
                float e1 = s_pool[EIDX(1, h, s)];
                float p0 = k0 ? e0 : 0.f;
                float p1 = k1 ? e1 : 0.f;
                ps0[h] += p0; ws0_[h] += p0 * vv;
                ps1[h] += p1; ws1_[h] += p1 * vv;
            }
        }
#pragma unroll
        for (int h = 0; h < HH; ++h) {
            ps0[h] += __shfl_xor(ps0[h], 32); ws0_[h] += __shfl_xor(ws0_[h], 32);
            ps1[h] += __shfl_xor(ps1[h], 32); ws1_[h] += __shfl_xor(ws1_[h], 32);
        }
        vsum += __shfl_xor(vsum, 32);
    }

    float tps = 0.f, tws = 0.f, tvs = 0.f;
    {
        int trr = lane >> 5, th = (lane >> 3) & 3, tj = lane & 7;
        float sad = s_sa[32];
        float lo = (trr ? qtr1 : qtr0) - sad, hi = (trr ? qtr1 : qtr0) + sad;
#pragma unroll
        for (int i = 0; i < 8; ++i) {
            int s = s0 + tj * 8 + i;
            float vv = value[(size_t)(b * SS + s) * DD + 32];
            float mv = maskp[(size_t)(b * SS + s) * DD + 32];
            float tv = s_tt[s];
            bool k = (mv != 0.f) & (tv >= lo) & (tv <= hi);
            float e = s_pool[EIDX(trr, th, s)];
            float p = k ? e : 0.f;
            tps += p; tws += p * vv; tvs += vv;
        }
#pragma unroll
        for (int off = 1; off < 8; off <<= 1) {
            tps += __shfl_xor(tps, off);
            tws += __shfl_xor(tws, off);
            tvs += __shfl_xor(tvs, off);
        }
    }
    __syncthreads();

    if (lane < 32) {
#pragma unroll
        for (int h = 0; h < HH; ++h) {
            s_pool[POOL_REDP + ((wv * 2 + 0) * HH + h) * 32 + lane] = ps0[h];
            s_pool[POOL_REDP + ((wv * 2 + 1) * HH + h) * 32 + lane] = ps1[h];
            s_pool[POOL_REDW + ((wv * 2 + 0) * HH + h) * 32 + lane] = ws0_[h];
            s_pool[POOL_REDW + ((wv * 2 + 1) * HH + h) * 32 + lane] = ws1_[h];
        }
        s_pool[POOL_REDV + wv * 32 + lane] = vsum;
    }
    if ((lane & 7) == 0) {
        int trr = lane >> 5, th = (lane >> 3) & 3;
        s_pool[POOL_R32P + (wv * 2 + trr) * HH + th] = tps;
        s_pool[POOL_R32W + (wv * 2 + trr) * HH + th] = tws;
        if (lane == 0) s_pool[POOL_R32V + wv] = tvs;
    }
    __syncthreads();

    if (tid < 256) {
        int rr = tid >> 7, hd = tid & 127, h = hd >> 5, dd = hd & 31;
        float p = 0.f, w = 0.f;
#pragma unroll
        for (int k = 0; k < 8; ++k) {
            p += s_pool[POOL_REDP + ((k * 2 + rr) * HH + h) * 32 + dd];
            w += s_pool[POOL_REDW + ((k * 2 + rr) * HH + h) * 32 + dd];
        }
        float xv;
        if (p > 0.f) xv = w / p;
        else {
            float va = 0.f;
#pragma unroll
            for (int k = 0; k < 8; ++k) va += s_pool[POOL_REDV + k * 32 + dd];
            xv = va * (1.0f / SS);
        }
        s_x[rr][h * DD + dd] = xv;
    } else if (tid < 264) {
        int t = tid - 256, rr = t >> 2, h = t & 3;
        float p = 0.f, w = 0.f;
#pragma unroll
        for (int k = 0; k < 8; ++k) {
            p += s_pool[POOL_R32P + (k * 2 + rr) * HH + h];
            w += s_pool[POOL_R32W + (k * 2 + rr) * HH + h];
        }
        float xv;
        if (p > 0.f) xv = w / p;
        else {
            float va = 0.f;
#pragma unroll
            for (int k = 0; k < 8; ++k) va += s_pool[POOL_R32V + k];
            xv = va * (1.0f / SS);
        }
        s_x[rr][h * DD + 32] = xv;
    }
    __syncthreads();

    {
        int g2 = tid >> 7;
        int rr = g2 >> 1, jg = g2 & 1;
        int n = tid & 127;
        float acc = 0.f;
#pragma unroll
        for (int j = 0; j < 66; ++j)
            acc += s_x[rr][jg * 66 + j] * wot[(jg * 66 + j) * NHH + n];
        s_part[g2][n] = acc;
    }
    __syncthreads();
    if (tid < 256) {
        int rr = tid >> 7, n = tid & 127;
        out[(b * RR + r0 + rr) * NHH + n] =
            bo[n] + s_part[rr * 2][n] + s_part[rr * 2 + 1][n];
    }
}

// ================================================================== launch
extern "C" void kernel_launch(void* const* d_in, const int* in_sizes, int n_in,
                              void* d_out, int out_size, void* d_ws, size_t ws_size,
                              hipStream_t stream) {
    const float* query   = (const float*)d_in[0];
    const float* key     = (const float*)d_in[1];
    const float* value   = (const float*)d_in[2];
    const float* maskp   = (const float*)d_in[3];
    const float* qt      = (const float*)d_in[4];
    const float* tt      = (const float*)d_in[5];
    const float* stridev = (const float*)d_in[6];
    const float* Wq      = (const float*)d_in[7];
    const float* bq      = (const float*)d_in[8];
    const float* Wk      = (const float*)d_in[9];
    const float* bk      = (const float*)d_in[10];
    const float* Wr      = (const float*)d_in[11];
    const float* brv     = (const float*)d_in[12];
    const float* Wo      = (const float*)d_in[13];
    const float* bo      = (const float*)d_in[14];

    float* out = (float*)d_out;               // 131072 out + 33 sa
    float* ws  = (float*)d_ws;

    // host-side occupancy check (pure queries; graph-capture safe)
    int dev = 0, numCU = 0, maxb = 0;
    hipGetDevice(&dev);
    hipDeviceGetAttribute(&numCU, hipDeviceAttributeMultiprocessorCount, dev);
    hipOccupancyMaxActiveBlocksPerMultiprocessor(&maxb, mega_kernel, 512, 0);

    if (maxb > 0 && numCU > 0 && (long)maxb * numCU >= BB * 64) {
        void* args[] = {
            (void*)&query, (void*)&key, (void*)&value, (void*)&maskp,
            (void*)&qt, (void*)&tt, (void*)&stridev,
            (void*)&Wq, (void*)&bq, (void*)&Wk, (void*)&bk,
            (void*)&Wr, (void*)&brv, (void*)&Wo, (void*)&bo,
            (void*)&ws, (void*)&out };
        hipLaunchCooperativeKernel(mega_kernel, dim3(BB * 64), dim3(512),
                                   args, 0, stream);
    } else {
        prep_kernel<<<NB_PREP, 256, 0, stream>>>(
            query, key, Wq, bq, Wk, bk, Wo, ws);
        fused_kernel<<<BB * 64, 512, 0, stream>>>(
            ws + WS_QP, ws + WS_KT, value, maskp, tt, qt,
            stridev, Wr, brv, ws + WS_WOT, bo, out);
    }
}